// Round 1
// baseline (2785.682 us; speedup 1.0000x reference)
//
#include <hip/hip_runtime.h>

#define CAP 32

// ---------------------------------------------------------------------------
// Kernel 1: runtime sparsification of W1 (general; for this input nnz=1/row).
// ---------------------------------------------------------------------------
__global__ void sparsify_kernel(const float* __restrict__ W1, int N,
                                int* __restrict__ cnts, int* __restrict__ cols,
                                float* __restrict__ wts) {
  __shared__ int scnt;
  const int row = blockIdx.x;
  if (threadIdx.x == 0) scnt = 0;
  __syncthreads();
  const float* wr = W1 + (long)row * N;
  for (int k = threadIdx.x; k < N; k += blockDim.x) {
    float w = wr[k];
    if (w != 0.0f) {
      int slot = atomicAdd(&scnt, 1);
      if (slot < CAP) {
        cols[row * CAP + slot] = k;
        wts[row * CAP + slot] = w;
      }
    }
  }
  __syncthreads();
  if (threadIdx.x == 0) {
    cnts[row] = scnt;
    if (scnt == 0) { cols[row * CAP] = 0; wts[row * CAP] = 0.0f; }
  }
}

// ---------------------------------------------------------------------------
// Kernel 2: warm input_batch into LLC (Infinity Cache) so the latency-bound
// recurrence sees L3-hit latency instead of ~900-cyc HBM misses.
// ---------------------------------------------------------------------------
__global__ void touch_kernel(const float4* __restrict__ x4, long n4,
                             float* __restrict__ dump) {
  long i = (long)blockIdx.x * blockDim.x + threadIdx.x;
  const long stride = (long)gridDim.x * blockDim.x;
  float acc = 0.f;
  for (; i < n4; i += stride) {
    float4 v = x4[i];
    acc += v.x + v.y + v.z + v.w;
  }
  // data-dependent store defeats DCE; in practice never taken
  if (acc == 1234.56789f) dump[blockIdx.x & 1023] = acc;
}

// ---------------------------------------------------------------------------
// Kernel 3: the serial Izhikevich recurrence, one thread per neuron.
// Bitwise replication of numpy op order; fp contraction OFF.
// ---------------------------------------------------------------------------
__global__ void __launch_bounds__(64) izh_kernel(
    const float* __restrict__ X, const float* __restrict__ state,
    const float* __restrict__ a, const float* __restrict__ b,
    const float* __restrict__ c, const float* __restrict__ d,
    const float* __restrict__ th, const float* __restrict__ dtv,
    const float* __restrict__ W1,
    const int* __restrict__ cnts, const int* __restrict__ cols,
    const float* __restrict__ wts,
    float* __restrict__ o_s, float* __restrict__ o_st,
    int T, int N)
{
#pragma clang fp contract(off)
  const int gn = blockIdx.x * blockDim.x + threadIdx.x;
  if (gn >= N) return;
  float v = state[gn];
  float u = state[N + gn];
  const float an = a[gn], bn = b[gn], cn = c[gn], dn = d[gn];
  const float thn = th[gn], dtn = dtv[gn];
  const float Pn = dtn * an;       // dt*a hoisted: same operands -> same rounding
  const int cnt = cnts[gn];
  const int c0 = cols[gn * CAP];
  const float w0 = wts[gn * CAP];

  float* ps = o_s + gn;            // outputs  [T,N]
  float* pv = o_st + gn;           // states v [T,2,N]
  float* pu = o_st + N + gn;       // states u
  const long N2 = 2L * N;

  if (cnt == 1 && dtn == 1.0f) {
    // fast path: single synapse, dt==1 (mul by 1.0f is exact -> skip it)
    const float* xp = X + c0;
    constexpr int PF = 32;          // rolling register prefetch depth
    float xbuf[PF];
#pragma unroll
    for (int i = 0; i < PF; ++i) xbuf[i] = (i < T) ? xp[(long)i * N] : 0.0f;
    int t0 = 0;
    for (; t0 + PF <= T; t0 += PF) {
#pragma unroll
      for (int i = 0; i < PF; ++i) {
        const int t = t0 + i;
        const float xv = xbuf[i];
        const int tnx = t + PF;
        if (tnx < T) xbuf[i] = xp[(long)tnx * N];
        const float I = w0 * xv;               // == f32(W1[n,n]*x) exactly
        // v + dt*(0.04*v*v + 5.0*v + 140.0 - u + I), numpy left-assoc order
        float t1 = 0.04f * v;
        float t2 = t1 * v;
        float t3 = 5.0f * v;
        float t4 = t2 + t3;
        float t5 = t4 + 140.0f;
        float t6 = t5 - u;
        float t7 = t6 + I;
        float vn = v + t7;                     // dt==1: mul skipped (exact)
        // u + (dt*a)*(b*v - u)
        float q1 = bn * v;
        float q2 = q1 - u;
        float q3 = Pn * q2;
        float un = u + q3;
        float df = vn - thn;
        bool sp = df > 0.0f;
        v = sp ? cn : vn;                      // == vn*(1-s)+c*s bitwise
        u = un + (sp ? dn : 0.0f);             // == un + d*s
        ps[(long)t * N]  = sp ? 1.0f : 0.0f;
        pv[(long)t * N2] = v;
        pu[(long)t * N2] = u;
      }
    }
    for (int t = t0; t < T; ++t) {             // tail (unused when T%32==0)
      const float xv = xp[(long)t * N];
      const float I = w0 * xv;
      float t1 = 0.04f * v; float t2 = t1 * v; float t3 = 5.0f * v;
      float t4 = t2 + t3; float t5 = t4 + 140.0f; float t6 = t5 - u;
      float t7 = t6 + I; float vn = v + t7;
      float q1 = bn * v; float q2 = q1 - u; float q3 = Pn * q2; float un = u + q3;
      float df = vn - thn; bool sp = df > 0.0f;
      v = sp ? cn : vn; u = un + (sp ? dn : 0.0f);
      ps[(long)t * N]  = sp ? 1.0f : 0.0f;
      pv[(long)t * N2] = v; pu[(long)t * N2] = u;
    }
  } else {
    // general path: sparse rows up to CAP nonzeros, dense fallback above that
    for (int t = 0; t < T; ++t) {
      float I = 0.0f;
      if (cnt <= CAP) {
        for (int j = 0; j < cnt; ++j)
          I = I + wts[gn * CAP + j] * X[(long)t * N + cols[gn * CAP + j]];
      } else {
        const float* wr = W1 + (long)gn * N;
        const float* xr = X + (long)t * N;
        for (int k = 0; k < N; ++k) I = I + wr[k] * xr[k];
      }
      float t1 = 0.04f * v; float t2 = t1 * v; float t3 = 5.0f * v;
      float t4 = t2 + t3; float t5 = t4 + 140.0f; float t6 = t5 - u;
      float t7 = t6 + I; float t8 = dtn * t7; float vn = v + t8;
      float q1 = bn * v; float q2 = q1 - u; float q3 = Pn * q2; float un = u + q3;
      float df = vn - thn; bool sp = df > 0.0f;
      v = sp ? cn : vn; u = un + (sp ? dn : 0.0f);
      ps[(long)t * N]  = sp ? 1.0f : 0.0f;
      pv[(long)t * N2] = v; pu[(long)t * N2] = u;
    }
  }
}

// ---------------------------------------------------------------------------
// Kernel 4: r[t] = W2 @ s[t]  (exact: terms are 20*{0,1}, sums < 2^24)
// ---------------------------------------------------------------------------
__global__ void decode_dot_kernel(const float* __restrict__ o_s,
                                  const float* __restrict__ W2,
                                  float* __restrict__ r, int N) {
  const int t = blockIdx.x;
  const float* srow = o_s + (long)t * N;
  float p = 0.0f;
  for (int n = threadIdx.x; n < N; n += blockDim.x)
    p += W2[n] * srow[n];
  for (int off = 32; off > 0; off >>= 1) p += __shfl_down(p, off);
  __shared__ float red[4];
  if ((threadIdx.x & 63) == 0) red[threadIdx.x >> 6] = p;
  __syncthreads();
  if (threadIdx.x == 0) {
    float tot = 0.f;
    const int nw = blockDim.x >> 6;
    for (int w = 0; w < nw; ++w) tot += red[w];
    r[t] = tot;
  }
}

// ---------------------------------------------------------------------------
// Kernel 5: dm[t] = leak*dm[t-1] + r[t], chunked affine scan (1 block, 64 thr)
// Tolerance on decoded output is large; reassociation across chunks is fine.
// ---------------------------------------------------------------------------
__global__ void decode_scan_kernel(const float* __restrict__ r,
                                   const float* __restrict__ leakp,
                                   float* __restrict__ out, int T) {
  __shared__ float Bsh[64], Ssh[64];
  const float leakv = leakp[0];
  const int i = threadIdx.x;                 // 0..63
  const int chunk = (T + 63) / 64;
  const int t0 = i * chunk;
  float B = 0.0f;
  for (int j = 0; j < chunk; ++j) {
    int t = t0 + j;
    if (t < T) B = leakv * B + r[t];
  }
  Bsh[i] = B;
  // A = leak^chunk by binary exponentiation
  float A = 1.0f, p = leakv; int e = chunk;
  while (e) { if (e & 1) A *= p; p *= p; e >>= 1; }
  __syncthreads();
  if (i == 0) {
    float dm = 0.0f;
    for (int k = 0; k < 64; ++k) { Ssh[k] = dm; dm = A * dm + Bsh[k]; }
  }
  __syncthreads();
  float dm = Ssh[i];
  for (int j = 0; j < chunk; ++j) {
    int t = t0 + j;
    if (t < T) { dm = leakv * dm + r[t]; out[t] = dm; }
  }
}

// ---------------------------------------------------------------------------
extern "C" void kernel_launch(void* const* d_in, const int* in_sizes, int n_in,
                              void* d_out, int out_size, void* d_ws, size_t ws_size,
                              hipStream_t stream) {
  const float* X  = (const float*)d_in[0];
  const float* st = (const float*)d_in[1];
  const float* W1 = (const float*)d_in[2];
  const float* W2 = (const float*)d_in[3];
  const float* a  = (const float*)d_in[4];
  const float* b  = (const float*)d_in[5];
  const float* c  = (const float*)d_in[6];
  const float* d  = (const float*)d_in[7];
  const float* th = (const float*)d_in[8];
  const float* dt = (const float*)d_in[9];
  const float* lk = (const float*)d_in[10];
  const int N = in_sizes[4];          // a has N elements
  const int T = in_sizes[0] / N;

  float* o_s  = (float*)d_out;               // outputs  [T,N]
  float* o_st = o_s + (long)T * N;           // states   [T,2,N]
  float* o_dm = o_st + 2L * (long)T * N;     // decoded  [T,1]

  int*   cnts = (int*)d_ws;                  // N
  int*   cols = cnts + N;                    // N*CAP
  float* wts  = (float*)(cols + (long)N * CAP); // N*CAP
  float* rbuf = wts + (long)N * CAP;         // T
  float* dump = rbuf + T;                    // toucher sink

  sparsify_kernel<<<N, 256, 0, stream>>>(W1, N, cnts, cols, wts);
  const long n4 = ((long)T * N) / 4;
  touch_kernel<<<1024, 256, 0, stream>>>((const float4*)X, n4, dump);
  izh_kernel<<<(N + 63) / 64, 64, 0, stream>>>(X, st, a, b, c, d, th, dt, W1,
                                               cnts, cols, wts, o_s, o_st, T, N);
  decode_dot_kernel<<<T, 256, 0, stream>>>(o_s, W2, rbuf, N);
  decode_scan_kernel<<<1, 64, 0, stream>>>(rbuf, lk, o_dm, T);
}

// Round 2
// 700.551 us; speedup vs baseline: 3.9764x; 3.9764x over previous
//
#include <hip/hip_runtime.h>

#define CAP 32

// ---------------------------------------------------------------------------
// Kernel 1: runtime sparsification of W1 (general; for this input nnz=1/row).
// ---------------------------------------------------------------------------
__global__ void sparsify_kernel(const float* __restrict__ W1, int N,
                                int* __restrict__ cnts, int* __restrict__ cols,
                                float* __restrict__ wts) {
  __shared__ int scnt;
  const int row = blockIdx.x;
  if (threadIdx.x == 0) scnt = 0;
  __syncthreads();
  const float* wr = W1 + (long)row * N;
  for (int k = threadIdx.x; k < N; k += blockDim.x) {
    float w = wr[k];
    if (w != 0.0f) {
      int slot = atomicAdd(&scnt, 1);
      if (slot < CAP) {
        cols[row * CAP + slot] = k;
        wts[row * CAP + slot] = w;
      }
    }
  }
  __syncthreads();
  if (threadIdx.x == 0) {
    cnts[row] = scnt;
    if (scnt == 0) { cols[row * CAP] = 0; wts[row * CAP] = 0.0f; }
  }
}

// ---------------------------------------------------------------------------
// Kernel 2: warm input_batch into LLC so the recurrence's prefetch loads see
// LLC-hit latency instead of ~900-cyc HBM misses.
// ---------------------------------------------------------------------------
__global__ void touch_kernel(const float4* __restrict__ x4, long n4,
                             float* __restrict__ dump) {
  long i = (long)blockIdx.x * blockDim.x + threadIdx.x;
  const long stride = (long)gridDim.x * blockDim.x;
  float acc = 0.f;
  for (; i < n4; i += stride) {
    float4 v = x4[i];
    acc += v.x + v.y + v.z + v.w;
  }
  if (acc == 1234.56789f) dump[blockIdx.x & 1023] = acc;  // defeat DCE
}

// ---------------------------------------------------------------------------
// Kernel 3: serial Izhikevich recurrence, one thread per neuron.
// Bitwise replication of numpy op order; fp contraction OFF.
// Batched K-step phases: prefetch(regs, dbuf) -> compute(no vmem) -> burst
// stores. This keeps vmcnt-expressible and moves all WAR register-reuse
// waits >= 1 batch (~700 cyc) after issue, so they're free.
// ---------------------------------------------------------------------------
#define IZH_STEP(xv, sv_, vv_, uv_)              \
  {                                              \
    const float I = w0 * (xv);                   \
    float t1 = 0.04f * v;                        \
    float t2 = t1 * v;                           \
    float t3 = 5.0f * v;                         \
    float t4 = t2 + t3;                          \
    float t5 = t4 + 140.0f;                      \
    float t6 = t5 - u;                           \
    float t7 = t6 + I;                           \
    float vn = v + t7;      /* dt==1: exact */   \
    float q1 = bn * v;                           \
    float q2 = q1 - u;                           \
    float q3 = Pn * q2;                          \
    float un = u + q3;                           \
    float df = vn - thn;                         \
    bool sp = df > 0.0f;                         \
    v = sp ? cn : vn;       /* == vn*(1-s)+c*s */\
    u = un + (sp ? dn : 0.0f);                   \
    sv_ = sp ? 1.0f : 0.0f;                      \
    vv_ = v; uv_ = u;                            \
  }

__global__ void __launch_bounds__(64) izh_kernel(
    const float* __restrict__ X, const float* __restrict__ state,
    const float* __restrict__ a, const float* __restrict__ b,
    const float* __restrict__ c, const float* __restrict__ d,
    const float* __restrict__ th, const float* __restrict__ dtv,
    const float* __restrict__ W1,
    const int* __restrict__ cnts, const int* __restrict__ cols,
    const float* __restrict__ wts,
    float* __restrict__ o_s, float* __restrict__ o_st,
    int T, int N)
{
#pragma clang fp contract(off)
  const int gn = blockIdx.x * blockDim.x + threadIdx.x;
  if (gn >= N) return;
  float v = state[gn];
  float u = state[N + gn];
  const float an = a[gn], bn = b[gn], cn = c[gn], dn = d[gn];
  const float thn = th[gn], dtn = dtv[gn];
  const float Pn = dtn * an;       // dt*a hoisted: same operands -> same rounding
  const int cnt = cnts[gn];
  const int c0 = cols[gn * CAP];
  const float w0 = wts[gn * CAP];

  float* ps = o_s + gn;            // outputs  [T,N]
  float* pv = o_st + gn;           // states v [T,2,N]
  float* pu = o_st + N + gn;       // states u
  const long N2 = 2L * N;

  if (cnt == 1 && dtn == 1.0f) {
    const float* xp = X + c0;
    constexpr int K = 16;
    float xa[K], xb[K];            // double-buffered x prefetch
    float sv[K], vv[K], uv[K];     // staged outputs (registers only)
#pragma unroll
    for (int i = 0; i < K; ++i) xa[i] = (i < T) ? xp[(long)i * N] : 0.0f;
    int t0 = 0;
    for (; t0 + 2 * K <= T; ) {
      // ---- batch A: uses xa, prefetches xb ----
#pragma unroll
      for (int i = 0; i < K; ++i) xb[i] = xp[(long)(t0 + K + i) * N];
#pragma unroll
      for (int i = 0; i < K; ++i) IZH_STEP(xa[i], sv[i], vv[i], uv[i]);
#pragma unroll
      for (int i = 0; i < K; ++i) ps[(long)(t0 + i) * N]  = sv[i];
#pragma unroll
      for (int i = 0; i < K; ++i) pv[(long)(t0 + i) * N2] = vv[i];
#pragma unroll
      for (int i = 0; i < K; ++i) pu[(long)(t0 + i) * N2] = uv[i];
      t0 += K;
      // ---- batch B: uses xb, prefetches xa (guarded) ----
#pragma unroll
      for (int i = 0; i < K; ++i) {
        const int tt = t0 + K + i;
        xa[i] = (tt < T) ? xp[(long)tt * N] : 0.0f;
      }
#pragma unroll
      for (int i = 0; i < K; ++i) IZH_STEP(xb[i], sv[i], vv[i], uv[i]);
#pragma unroll
      for (int i = 0; i < K; ++i) ps[(long)(t0 + i) * N]  = sv[i];
#pragma unroll
      for (int i = 0; i < K; ++i) pv[(long)(t0 + i) * N2] = vv[i];
#pragma unroll
      for (int i = 0; i < K; ++i) pu[(long)(t0 + i) * N2] = uv[i];
      t0 += K;
    }
    for (int t = t0; t < T; ++t) {             // tail (unused when T%32==0)
      const float xv = xp[(long)t * N];
      float s_, v_, u_;
      IZH_STEP(xv, s_, v_, u_);
      ps[(long)t * N]  = s_;
      pv[(long)t * N2] = v_;
      pu[(long)t * N2] = u_;
    }
  } else {
    // general path: sparse rows up to CAP nonzeros, dense fallback above that
    for (int t = 0; t < T; ++t) {
      float I = 0.0f;
      if (cnt <= CAP) {
        for (int j = 0; j < cnt; ++j)
          I = I + wts[gn * CAP + j] * X[(long)t * N + cols[gn * CAP + j]];
      } else {
        const float* wr = W1 + (long)gn * N;
        const float* xr = X + (long)t * N;
        for (int k = 0; k < N; ++k) I = I + wr[k] * xr[k];
      }
      float t1 = 0.04f * v; float t2 = t1 * v; float t3 = 5.0f * v;
      float t4 = t2 + t3; float t5 = t4 + 140.0f; float t6 = t5 - u;
      float t7 = t6 + I; float t8 = dtn * t7; float vn = v + t8;
      float q1 = bn * v; float q2 = q1 - u; float q3 = Pn * q2; float un = u + q3;
      float df = vn - thn; bool sp = df > 0.0f;
      v = sp ? cn : vn; u = un + (sp ? dn : 0.0f);
      ps[(long)t * N]  = sp ? 1.0f : 0.0f;
      pv[(long)t * N2] = v; pu[(long)t * N2] = u;
    }
  }
}

// ---------------------------------------------------------------------------
// Kernel 4: r[t] = W2 @ s[t]  (exact: terms are 20*{0,1}, sums < 2^24)
// ---------------------------------------------------------------------------
__global__ void decode_dot_kernel(const float* __restrict__ o_s,
                                  const float* __restrict__ W2,
                                  float* __restrict__ r, int N) {
  const int t = blockIdx.x;
  const float* srow = o_s + (long)t * N;
  float p = 0.0f;
  for (int n = threadIdx.x; n < N; n += blockDim.x)
    p += W2[n] * srow[n];
  for (int off = 32; off > 0; off >>= 1) p += __shfl_down(p, off);
  __shared__ float red[4];
  if ((threadIdx.x & 63) == 0) red[threadIdx.x >> 6] = p;
  __syncthreads();
  if (threadIdx.x == 0) {
    float tot = 0.f;
    const int nw = blockDim.x >> 6;
    for (int w = 0; w < nw; ++w) tot += red[w];
    r[t] = tot;
  }
}

// ---------------------------------------------------------------------------
// Kernel 5: dm[t] = leak*dm[t-1] + r[t], chunked affine scan (1 block, 64 thr)
// Tolerance on decoded output is large; reassociation across chunks is fine.
// ---------------------------------------------------------------------------
__global__ void decode_scan_kernel(const float* __restrict__ r,
                                   const float* __restrict__ leakp,
                                   float* __restrict__ out, int T) {
  __shared__ float Bsh[64], Ssh[64];
  const float leakv = leakp[0];
  const int i = threadIdx.x;                 // 0..63
  const int chunk = (T + 63) / 64;
  const int t0 = i * chunk;
  float B = 0.0f;
  for (int j = 0; j < chunk; ++j) {
    int t = t0 + j;
    if (t < T) B = leakv * B + r[t];
  }
  Bsh[i] = B;
  float A = 1.0f, p = leakv; int e = chunk;
  while (e) { if (e & 1) A *= p; p *= p; e >>= 1; }
  __syncthreads();
  if (i == 0) {
    float dm = 0.0f;
    for (int k = 0; k < 64; ++k) { Ssh[k] = dm; dm = A * dm + Bsh[k]; }
  }
  __syncthreads();
  float dm = Ssh[i];
  for (int j = 0; j < chunk; ++j) {
    int t = t0 + j;
    if (t < T) { dm = leakv * dm + r[t]; out[t] = dm; }
  }
}

// ---------------------------------------------------------------------------
extern "C" void kernel_launch(void* const* d_in, const int* in_sizes, int n_in,
                              void* d_out, int out_size, void* d_ws, size_t ws_size,
                              hipStream_t stream) {
  const float* X  = (const float*)d_in[0];
  const float* st = (const float*)d_in[1];
  const float* W1 = (const float*)d_in[2];
  const float* W2 = (const float*)d_in[3];
  const float* a  = (const float*)d_in[4];
  const float* b  = (const float*)d_in[5];
  const float* c  = (const float*)d_in[6];
  const float* d  = (const float*)d_in[7];
  const float* th = (const float*)d_in[8];
  const float* dt = (const float*)d_in[9];
  const float* lk = (const float*)d_in[10];
  const int N = in_sizes[4];          // a has N elements
  const int T = in_sizes[0] / N;

  float* o_s  = (float*)d_out;               // outputs  [T,N]
  float* o_st = o_s + (long)T * N;           // states   [T,2,N]
  float* o_dm = o_st + 2L * (long)T * N;     // decoded  [T,1]

  int*   cnts = (int*)d_ws;                  // N
  int*   cols = cnts + N;                    // N*CAP
  float* wts  = (float*)(cols + (long)N * CAP); // N*CAP
  float* rbuf = wts + (long)N * CAP;         // T
  float* dump = rbuf + T;                    // toucher sink

  sparsify_kernel<<<N, 256, 0, stream>>>(W1, N, cnts, cols, wts);
  const long n4 = ((long)T * N) / 4;
  touch_kernel<<<1024, 256, 0, stream>>>((const float4*)X, n4, dump);
  izh_kernel<<<(N + 63) / 64, 64, 0, stream>>>(X, st, a, b, c, d, th, dt, W1,
                                               cnts, cols, wts, o_s, o_st, T, N);
  decode_dot_kernel<<<T, 256, 0, stream>>>(o_s, W2, rbuf, N);
  decode_scan_kernel<<<1, 64, 0, stream>>>(rbuf, lk, o_dm, T);
}

// Round 3
// 590.498 us; speedup vs baseline: 4.7175x; 1.1864x over previous
//
#include <hip/hip_runtime.h>

#define CAP 32
#define K 16

// ---------------------------------------------------------------------------
// Kernel 1: runtime sparsification of W1 (general; for this input nnz=1/row).
// ---------------------------------------------------------------------------
__global__ void sparsify_kernel(const float* __restrict__ W1, int N,
                                int* __restrict__ cnts, int* __restrict__ cols,
                                float* __restrict__ wts) {
  __shared__ int scnt;
  const int row = blockIdx.x;
  if (threadIdx.x == 0) scnt = 0;
  __syncthreads();
  const float* wr = W1 + (long)row * N;
  for (int k = threadIdx.x; k < N; k += blockDim.x) {
    float w = wr[k];
    if (w != 0.0f) {
      int slot = atomicAdd(&scnt, 1);
      if (slot < CAP) {
        cols[row * CAP + slot] = k;
        wts[row * CAP + slot] = w;
      }
    }
  }
  __syncthreads();
  if (threadIdx.x == 0) {
    cnts[row] = scnt;
    if (scnt == 0) { cols[row * CAP] = 0; wts[row * CAP] = 0.0f; }
  }
}

// ---------------------------------------------------------------------------
// Kernel 2: warm input_batch into LLC so the loader's distance-1-batch loads
// retire well inside one batch (~300 cyc LLC vs ~900 cyc HBM).
// ---------------------------------------------------------------------------
__global__ void touch_kernel(const float4* __restrict__ x4, long n4,
                             float* __restrict__ dump) {
  long i = (long)blockIdx.x * blockDim.x + threadIdx.x;
  const long stride = (long)gridDim.x * blockDim.x;
  float acc = 0.f;
  for (; i < n4; i += stride) {
    float4 v = x4[i];
    acc += v.x + v.y + v.z + v.w;
  }
  if (acc == 1234.56789f) dump[blockIdx.x & 1023] = acc;  // defeat DCE
}

// ---------------------------------------------------------------------------
// One Izhikevich step, bitwise numpy op order (contract off at kernel scope).
// Updates v,u in place; writes spike value to sout.
// ---------------------------------------------------------------------------
#define IZH_STEP(xv, sout)                        \
  {                                               \
    const float I = w0 * (xv);                    \
    float t1 = 0.04f * v;                         \
    float t2 = t1 * v;                            \
    float t3 = 5.0f * v;                          \
    float t4 = t2 + t3;                           \
    float t5 = t4 + 140.0f;                       \
    float t6 = t5 - u;                            \
    float t7 = t6 + I;                            \
    float vn = v + t7;      /* dt==1: exact */    \
    float q1 = bn * v;                            \
    float q2 = q1 - u;                            \
    float q3 = Pn * q2;                           \
    float un = u + q3;                            \
    float df = vn - thn;                          \
    bool sp = df > 0.0f;                          \
    v = sp ? cn : vn;       /* == vn*(1-s)+c*s */ \
    u = un + (sp ? dn : 0.0f); /* == un + d*s */  \
    sout = sp ? 1.0f : 0.0f;                      \
  }

// ---------------------------------------------------------------------------
// Kernel 3: producer/consumer pipelined recurrence.
// Block = 256 thr (4 waves) per 64 neurons; grid = N/64 blocks.
//   wave0: compute only (LDS in, LDS out; ZERO global-memory instructions)
//   wave1: x loader (distance-2 reg pipeline -> LDS) + s writer
//   wave2: v writer   wave3: u writer
// Writers store float4 rows (4 x dwordx4 insts per array per 16-step batch).
// ---------------------------------------------------------------------------
__global__ void __launch_bounds__(256) izh_pipe_kernel(
    const float* __restrict__ X, const float* __restrict__ state,
    const float* __restrict__ a, const float* __restrict__ b,
    const float* __restrict__ c, const float* __restrict__ d,
    const float* __restrict__ th, const float* __restrict__ dtv,
    const float* __restrict__ W1,
    const int* __restrict__ cnts, const int* __restrict__ cols,
    const float* __restrict__ wts,
    float* __restrict__ o_s, float* __restrict__ o_st,
    int T, int N)
{
#pragma clang fp contract(off)
  __shared__ float xbuf[2][K][64];        // staged x, double-buffered
  __shared__ float obuf[2][K][3][64];     // staged outputs: [buf][step][s,v,u][lane]
  __shared__ int s_fast;

  const int wid  = threadIdx.x >> 6;
  const int lane = threadIdx.x & 63;
  const int base = blockIdx.x * 64;
  const int gn   = base + lane;           // wave0 / loader lane's neuron
  const int B    = T / K;                 // full batches
  const long N2  = 2L * N;

  // ---- block-uniform path decision (wave0 ballots, all read s_fast) ----
  if (wid == 0) {
    bool elig = (base + 64 <= N) && ((N & 3) == 0);
    if (elig) elig = (cnts[gn] == 1) && (dtv[gn] == 1.0f);
    unsigned long long m = __ballot(elig);
    if (lane == 0) s_fast = (m == ~0ULL) ? 1 : 0;
  }
  __syncthreads();

  if (s_fast) {
    // ---- per-role persistent registers ----
    float v = 0.f, u = 0.f, an = 0.f, bn = 0.f, cn = 0.f, dn = 0.f;
    float thn = 0.f, Pn = 0.f, w0 = 0.f;
    int c0g = 0;
    float xreg[K];
    int c0l = 0;

    if (wid == 0) {
      v = state[gn]; u = state[N + gn];
      an = a[gn]; bn = b[gn]; cn = c[gn]; dn = d[gn]; thn = th[gn];
      Pn = dtv[gn] * an;                 // same operands/order as ref's dt*a
      w0 = wts[gn * CAP];
      c0g = cols[gn * CAP];              // for the tail path only
    } else if (wid == 1) {
      c0l = cols[gn * CAP];
      if (B >= 1) {                      // batch 0 -> LDS now
        float r0[K];
#pragma unroll
        for (int i = 0; i < K; ++i) r0[i] = X[(size_t)i * N + c0l];
#pragma unroll
        for (int i = 0; i < K; ++i) xbuf[0][i][lane] = r0[i];
      }
      if (B >= 2) {                      // batch 1 -> regs (LDS at iter 0)
#pragma unroll
        for (int i = 0; i < K; ++i) xreg[i] = X[(size_t)(K + i) * N + c0l];
      }
    }
    __syncthreads();

    // writer helper: 16 rows of batch q, array cidx, dest P (row stride RS)
    auto store4 = [&](float* P, long RS, int q, int cidx) {
      const int r = lane >> 4, j = lane & 15;
      const int t0 = q * K;
#pragma unroll
      for (int i = 0; i < K; i += 4) {
        const int t = t0 + i + r;
        float4 val = *(const float4*)&obuf[q & 1][i + r][cidx][4 * j];
        *(float4*)(P + (size_t)t * RS + base + 4 * j) = val;
      }
    };

    for (int k = 0; k < B; ++k) {
      if (wid == 0) {
        // -------- compute: LDS -> 16 steps -> LDS --------
        float xv[K];
#pragma unroll
        for (int i = 0; i < K; ++i) xv[i] = xbuf[k & 1][i][lane];
#pragma unroll
        for (int i = 0; i < K; ++i) {
          float s_;
          IZH_STEP(xv[i], s_);
          obuf[k & 1][i][0][lane] = s_;
          obuf[k & 1][i][1][lane] = v;
          obuf[k & 1][i][2][lane] = u;
        }
      } else if (wid == 1) {
        // -------- loader: LDS-write batch k+1, issue loads batch k+2 ------
        if (k + 1 < B) {
#pragma unroll
          for (int i = 0; i < K; ++i) xbuf[(k + 1) & 1][i][lane] = xreg[i];
        }
        if (k + 2 < B) {
#pragma unroll
          for (int i = 0; i < K; ++i)
            xreg[i] = X[(size_t)((k + 2) * K + i) * N + c0l];
        }
        if (k > 0) store4(o_s, N, k - 1, 0);          // s writer
      } else if (wid == 2) {
        if (k > 0) store4(o_st, N2, k - 1, 1);        // v writer
      } else {
        if (k > 0) store4(o_st + N, N2, k - 1, 2);    // u writer
      }
      __syncthreads();
    }

    // -------- epilogue: drain last staged batch --------
    if (B > 0) {
      if (wid == 1)      store4(o_s, N, B - 1, 0);
      else if (wid == 2) store4(o_st, N2, B - 1, 1);
      else if (wid == 3) store4(o_st + N, N2, B - 1, 2);
    }

    // -------- tail (T % K != 0): wave0, direct global (rare) --------
    if (wid == 0) {
      const float* xp = X + c0g;
      for (int t = B * K; t < T; ++t) {
        const float xv = xp[(size_t)t * N];
        float s_;
        IZH_STEP(xv, s_);
        o_s[(size_t)t * N + gn] = s_;
        o_st[(size_t)t * N2 + gn] = v;
        o_st[(size_t)t * N2 + N + gn] = u;
      }
    }
  } else {
    // ---- general fallback: wave0 threads only, any cnt / dt ----
    if (wid != 0 || gn >= N) return;
    float v = state[gn], u = state[N + gn];
    const float an = a[gn], bn = b[gn], cn = c[gn], dn = d[gn];
    const float thn = th[gn], dtn = dtv[gn];
    const float Pn = dtn * an;
    const int cnt = cnts[gn];
    for (int t = 0; t < T; ++t) {
      float I = 0.0f;
      if (cnt <= CAP) {
        for (int j = 0; j < cnt; ++j)
          I = I + wts[gn * CAP + j] * X[(size_t)t * N + cols[gn * CAP + j]];
      } else {
        const float* wr = W1 + (size_t)gn * N;
        const float* xr = X + (size_t)t * N;
        for (int kk = 0; kk < N; ++kk) I = I + wr[kk] * xr[kk];
      }
      float t1 = 0.04f * v; float t2 = t1 * v; float t3 = 5.0f * v;
      float t4 = t2 + t3; float t5 = t4 + 140.0f; float t6 = t5 - u;
      float t7 = t6 + I; float t8 = dtn * t7; float vn = v + t8;
      float q1 = bn * v; float q2 = q1 - u; float q3 = Pn * q2; float un = u + q3;
      float df = vn - thn; bool sp = df > 0.0f;
      v = sp ? cn : vn; u = un + (sp ? dn : 0.0f);
      o_s[(size_t)t * N + gn] = sp ? 1.0f : 0.0f;
      o_st[(size_t)t * N2 + gn] = v;
      o_st[(size_t)t * N2 + N + gn] = u;
    }
  }
}

// ---------------------------------------------------------------------------
// Kernel 4: r[t] = W2 @ s[t]  (exact: terms are 20*{0,1}, sums < 2^24)
// ---------------------------------------------------------------------------
__global__ void decode_dot_kernel(const float* __restrict__ o_s,
                                  const float* __restrict__ W2,
                                  float* __restrict__ r, int N) {
  const int t = blockIdx.x;
  const float* srow = o_s + (long)t * N;
  float p = 0.0f;
  for (int n = threadIdx.x; n < N; n += blockDim.x)
    p += W2[n] * srow[n];
  for (int off = 32; off > 0; off >>= 1) p += __shfl_down(p, off);
  __shared__ float red[4];
  if ((threadIdx.x & 63) == 0) red[threadIdx.x >> 6] = p;
  __syncthreads();
  if (threadIdx.x == 0) {
    float tot = 0.f;
    const int nw = blockDim.x >> 6;
    for (int w = 0; w < nw; ++w) tot += red[w];
    r[t] = tot;
  }
}

// ---------------------------------------------------------------------------
// Kernel 5: dm[t] = leak*dm[t-1] + r[t], chunked affine scan (1 block, 64 thr)
// Tolerance on decoded output is large; reassociation across chunks is fine.
// ---------------------------------------------------------------------------
__global__ void decode_scan_kernel(const float* __restrict__ r,
                                   const float* __restrict__ leakp,
                                   float* __restrict__ out, int T) {
  __shared__ float Bsh[64], Ssh[64];
  const float leakv = leakp[0];
  const int i = threadIdx.x;                 // 0..63
  const int chunk = (T + 63) / 64;
  const int t0 = i * chunk;
  float B = 0.0f;
  for (int j = 0; j < chunk; ++j) {
    int t = t0 + j;
    if (t < T) B = leakv * B + r[t];
  }
  Bsh[i] = B;
  float A = 1.0f, p = leakv; int e = chunk;
  while (e) { if (e & 1) A *= p; p *= p; e >>= 1; }
  __syncthreads();
  if (i == 0) {
    float dm = 0.0f;
    for (int k = 0; k < 64; ++k) { Ssh[k] = dm; dm = A * dm + Bsh[k]; }
  }
  __syncthreads();
  float dm = Ssh[i];
  for (int j = 0; j < chunk; ++j) {
    int t = t0 + j;
    if (t < T) { dm = leakv * dm + r[t]; out[t] = dm; }
  }
}

// ---------------------------------------------------------------------------
extern "C" void kernel_launch(void* const* d_in, const int* in_sizes, int n_in,
                              void* d_out, int out_size, void* d_ws, size_t ws_size,
                              hipStream_t stream) {
  const float* X  = (const float*)d_in[0];
  const float* st = (const float*)d_in[1];
  const float* W1 = (const float*)d_in[2];
  const float* W2 = (const float*)d_in[3];
  const float* a  = (const float*)d_in[4];
  const float* b  = (const float*)d_in[5];
  const float* c  = (const float*)d_in[6];
  const float* d  = (const float*)d_in[7];
  const float* th = (const float*)d_in[8];
  const float* dt = (const float*)d_in[9];
  const float* lk = (const float*)d_in[10];
  const int N = in_sizes[4];          // a has N elements
  const int T = in_sizes[0] / N;

  float* o_s  = (float*)d_out;               // outputs  [T,N]
  float* o_st = o_s + (long)T * N;           // states   [T,2,N]
  float* o_dm = o_st + 2L * (long)T * N;     // decoded  [T,1]

  int*   cnts = (int*)d_ws;                  // N
  int*   cols = cnts + N;                    // N*CAP
  float* wts  = (float*)(cols + (long)N * CAP); // N*CAP
  float* rbuf = wts + (long)N * CAP;         // T
  float* dump = rbuf + T;                    // toucher sink

  sparsify_kernel<<<N, 256, 0, stream>>>(W1, N, cnts, cols, wts);
  const long n4 = ((long)T * N) / 4;
  touch_kernel<<<1024, 256, 0, stream>>>((const float4*)X, n4, dump);
  const int nblk = (N + 63) / 64;
  izh_pipe_kernel<<<nblk, 256, 0, stream>>>(X, st, a, b, c, d, th, dt, W1,
                                            cnts, cols, wts, o_s, o_st, T, N);
  decode_dot_kernel<<<T, 256, 0, stream>>>(o_s, W2, rbuf, N);
  decode_scan_kernel<<<1, 64, 0, stream>>>(rbuf, lk, o_dm, T);
}